// Round 6
// baseline (12.654 us; speedup 1.0000x reference)
//
#include <hip/hip_runtime.h>

// WavetableModel: out[n] = sum_t exp(log_norm - 0.5*z^2) * table[t] / (peak+1e-8)
//   z=(t/4095-mu)/sigma, mu=frac((n+1)*|f0|), sigma=0.01+1e-8.
// Exp-free inner loop (verified R5, absmax 0.5):
//   weight(k+q) = [rk*g_k] * (r1*t_k)^q * C_q,  q=0..3
//   chunk stride 32 taps: rk*=R32 (per-sample), gch*=mch, mch*=MD, tch*=T32
// All loop constants via __expf (f32 HW exp) — R5's f64 exp() calls were the
// regression suspect (no f64 transcendental HW on gfx950).
// Staging: reg-staged float4 copy (R4 known-good; global_load_lds reverted).
// Window +-128 taps (3.125 sigma): truncation <=~0.09 abs vs threshold 2.05.
// Model: ~7.4us fixed graph/launch overhead; exec target ~1.2us (LDS-issue).

#define NS     32768
#define TS     4096
#define BLK    256
#define LPS    8                 // lanes per sample
#define SPB    (BLK / LPS)       // 32 samples per block
#define NBLK   (NS / SPB)        // 1024 blocks
#define HALF   128               // half-window in taps
#define NCHUNK 64                // float4 chunks per sample (256 taps)
#define TPAD   4224              // max read 3964+255=4219 < 4224

__global__ __launch_bounds__(BLK) void wt_kernel(const float* __restrict__ f0p,
                                                 const float* __restrict__ table,
                                                 float* __restrict__ out)
{
    __shared__ __align__(16) float tab[TPAD];
    const int tid = threadIdx.x;

    // ---- constants ----
    constexpr double SIGMA  = 0.01 + 1e-8;
    constexpr double INV_SG = 1.0 / SIGMA;
    constexpr double DZ     = 1.0 / (4095.0 * SIGMA);    // z step per tap
    constexpr double DZ2    = DZ * DZ;
    const float log_norm = 3.6862306527839187f;          // -ln(sigma)-0.5*ln(2pi)
    // f32 HW exp for all constants (v_exp_f32, ~1 slot each):
    const float C1  = __expf((float)(-0.5  * DZ2));
    const float C2  = __expf((float)(-2.0  * DZ2));
    const float C3  = __expf((float)(-4.5  * DZ2));
    const float T32 = __expf((float)(-32.0 * DZ2));
    const float MD  = __expf((float)(-1024.0 * DZ2));

    // ---- stage table -> LDS (reg-staged float4 copy, 4 iters/thread) ----
    {
        const float4* t4 = (const float4*)table;
        float4* s4 = (float4*)tab;
        #pragma unroll
        for (int i = tid; i < TS / 4; i += BLK) s4[i] = t4[i];
        if (tid < (TPAD - TS) / 4)
            s4[TS / 4 + tid] = make_float4(0.f, 0.f, 0.f, 0.f);
    }
    const float f0a = fabsf(f0p[0]);
    __syncthreads();

    const int g = blockIdx.x * BLK + tid;
    const int n = g >> 3;        // sample index
    const int j = g & (LPS - 1); // lane-within-sample

    // mu exactly (double): frac((n+1)*|f0|)
    const double mu = fmod((double)(n + 1) * (double)f0a, 1.0);

    // normalizer: window value at nearest grid point
    const int tc = (int)(mu * 4095.0 + 0.5);
    const float zsf = (float)(((double)tc * (1.0 / 4095.0) - mu) * INV_SG);
    const float peak = __expf(fmaf(-0.5f * zsf, zsf, log_norm));
    const float denom = peak + 1e-8f;

    int t0 = tc - HALF;
    t0 = (t0 < 0) ? 0 : t0;
    t0 &= ~3;                    // float4 alignment

    const double z0d = ((double)t0 * (1.0 / 4095.0) - mu) * INV_SG;
    const float  z0  = (float)z0d;
    const float  bb  = (float)(-z0d * DZ);               // ln R (per-tap log-step)

    const float e0  = __expf(fmaf(-0.5f * z0, z0, log_norm));
    const float r1  = __expf(bb);
    const float R32 = __expf(bb * 32.0f);
    const float k0f = (float)(4 * j);                    // lane start tap
    float rk  = __expf(bb * k0f);
    float tch = __expf((float)(-DZ2) * k0f);
    float gch = __expf((float)(-0.5 * DZ2) * k0f * k0f);
    float mch = __expf(fmaf((float)(-32.0 * DZ2), k0f, (float)(-512.0 * DZ2)));

    const float4* __restrict__ src = (const float4*)(tab + t0);
    float acc = 0.f;
    #pragma unroll
    for (int c = j; c < NCHUNK; c += LPS) {   // 8 chunks per lane, stride 32 taps
        const float4 v = src[c];
        const float A  = rk * gch;            // rk * g_k
        const float s  = r1 * tch;            // per-tap ratio at this k
        const float s2 = s * s;
        const float s3 = s2 * s;
        acc = fmaf(A,            v.x, acc);
        acc = fmaf(A * s  * C1,  v.y, acc);
        acc = fmaf(A * s2 * C2,  v.z, acc);
        acc = fmaf(A * s3 * C3,  v.w, acc);
        rk  *= R32;
        gch *= mch;
        mch *= MD;
        tch *= T32;
    }

    // reduce 8 lanes -> sample
    acc += __shfl_xor(acc, 1);
    acc += __shfl_xor(acc, 2);
    acc += __shfl_xor(acc, 4);
    if (j == 0) out[n] = acc * e0 / denom;
}

extern "C" void kernel_launch(void* const* d_in, const int* in_sizes, int n_in,
                              void* d_out, int out_size, void* d_ws, size_t ws_size,
                              hipStream_t stream)
{
    const float* f0    = (const float*)d_in[1];   // d_in[0] = x (unused by the math)
    const float* table = (const float*)d_in[2];
    float* out = (float*)d_out;
    wt_kernel<<<dim3(NBLK), dim3(BLK), 0, stream>>>(f0, table, out);
}

// Round 7
// 9.770 us; speedup vs baseline: 1.2952x; 1.2952x over previous
//
#include <hip/hip_runtime.h>

// WavetableModel: out[n] = sum_t exp(log_norm - 0.5*z^2) * table[t] / (peak+1e-8)
//   z=(t/4095-mu)/sigma, mu=frac((n+1)*|f0|), sigma=0.01+1e-8
// Exp-free inner loop: w_k = e0 * R^k * g_k with
//   e0 = exp(log_norm - 0.5*z0^2)  (per sample, hoisted to epilogue)
//   R  = exp(-z0*dz)               (geometric chain: 1 mul/tap)
//   g_k= exp(-0.5*dz^2*k^2)        (sample-independent 288-entry LDS table)
// Window +-144 taps (3.51 sigma): truncation <=0.05 abs vs threshold 2.05.
// BYTE-IDENTICAL RESUBMISSION OF R4 (measured 9.42us) — A/B against R5/R6's
// 12.2-12.7us to separate kernel regression from harness drift.

#define NS     32768
#define TS     4096
#define BLK    256
#define LPS    8                // lanes per sample
#define SPB    (BLK / LPS)      // 32 samples per block
#define NBLK   (NS / SPB)       // 1024 blocks
#define HALF   144              // half-window in taps
#define NCHUNK 72               // float4 chunks per sample (288 taps)
#define NTAP   (NCHUNK * 4)
#define TPAD   4352             // max read = 3948 + 287 = 4235 < 4352

__global__ __launch_bounds__(BLK) void wt_kernel(const float* __restrict__ f0p,
                                                 const float* __restrict__ table,
                                                 float* __restrict__ out)
{
    __shared__ __align__(16) float tab[TPAD];
    __shared__ __align__(16) float gtab[NTAP];
    const int tid = threadIdx.x;

    constexpr double SIGMA = 0.01 + 1e-8;
    constexpr double DZ    = 1.0 / (4095.0 * SIGMA);     // z step per tap
    constexpr float  GC    = (float)(-0.5 * DZ * DZ);    // g_k = exp(GC*k^2)
    const float log_norm = 3.6862306527839187f;          // -ln(sigma)-0.5*ln(2pi)

    {
        const float4* t4 = (const float4*)table;
        float4* s4 = (float4*)tab;
        #pragma unroll
        for (int i = tid; i < TS / 4; i += BLK) s4[i] = t4[i];
        for (int i = TS / 4 + tid; i < TPAD / 4; i += BLK)
            s4[i] = make_float4(0.f, 0.f, 0.f, 0.f);
        for (int k = tid; k < NTAP; k += BLK) {
            const float kf = (float)k;
            gtab[k] = __expf(GC * kf * kf);
        }
    }
    const float f0a = fabsf(f0p[0]);
    __syncthreads();

    const int g = blockIdx.x * BLK + tid;
    const int n = g >> 3;        // sample index
    const int j = g & (LPS - 1); // lane-within-sample

    // mu exactly (double): frac((n+1)*|f0|)
    const double mu = fmod((double)(n + 1) * (double)f0a, 1.0);

    // normalizer: window value at nearest grid point
    const int tc = (int)(mu * 4095.0 + 0.5);
    const float zsf = (float)(((double)tc * (1.0 / 4095.0) - mu) / SIGMA);
    const float peak = __expf(fmaf(-0.5f * zsf, zsf, log_norm));
    const float denom = peak + 1e-8f;

    int t0 = tc - HALF;
    t0 = (t0 < 0) ? 0 : t0;
    t0 &= ~3;                    // float4 alignment

    const double z0d = ((double)t0 * (1.0 / 4095.0) - mu) / SIGMA;
    const float  z0  = (float)z0d;
    const float  bb  = (float)(-z0d * DZ);               // ln R

    const float e0  = __expf(fmaf(-0.5f * z0, z0, log_norm));
    const float r1  = __expf(bb);                        // R
    const float r32 = __expf(bb * 32.0f);                // R^32 (lane chunk stride)
    float       rk  = __expf(bb * (float)(4 * j));       // R^(4j) start
    const float r2  = r1 * r1;
    const float r3  = r2 * r1;

    const float4* __restrict__ src = (const float4*)(tab + t0);
    const float4* __restrict__ gsrc = (const float4*)gtab;
    float acc = 0.f;
    #pragma unroll
    for (int c = j; c < NCHUNK; c += LPS) {   // 9 chunks per lane
        const float4 v  = src[c];
        const float4 gg = gsrc[c];
        const float w1 = rk * r1, w2 = rk * r2, w3 = rk * r3;
        acc = fmaf(rk * gg.x, v.x, acc);
        acc = fmaf(w1 * gg.y, v.y, acc);
        acc = fmaf(w2 * gg.z, v.z, acc);
        acc = fmaf(w3 * gg.w, v.w, acc);
        rk *= r32;
    }

    // reduce 8 lanes -> sample
    acc += __shfl_xor(acc, 1);
    acc += __shfl_xor(acc, 2);
    acc += __shfl_xor(acc, 4);
    if (j == 0) out[n] = acc * e0 / denom;
}

extern "C" void kernel_launch(void* const* d_in, const int* in_sizes, int n_in,
                              void* d_out, int out_size, void* d_ws, size_t ws_size,
                              hipStream_t stream)
{
    const float* f0    = (const float*)d_in[1];   // d_in[0] = x (unused by the math)
    const float* table = (const float*)d_in[2];
    float* out = (float*)d_out;
    wt_kernel<<<dim3(NBLK), dim3(BLK), 0, stream>>>(f0, table, out);
}